// Round 3
// baseline (287.981 us; speedup 1.0000x reference)
//
#include <hip/hip_runtime.h>
#include <math.h>

#define D_X      1024
#define D_TEXT   768
#define FDIM     1792
#define BATCH    256
#define M_EXP    16
#define HW_TOT   1024   // 32*32

// Output layout (flat f32): gates[4096] | moe_loss[1] | probs[4096] | top_idx[512]
#define OUT_GATES 0
#define OUT_LOSS  4096
#define OUT_PROBS 4097
#define OUT_IDX   8193

#define POOL_BLOCKS 2048
#define NROWS (BATCH * D_X)        // 262144

// ---------------------------------------------------------------------------
// Kernel 1: mean-pool x (B,1024,32,32) -> fused[:, :1024], persistent waves,
//           2 rows per wave per iter (8 float4 in flight); + degraded copy.
// ---------------------------------------------------------------------------
__global__ __launch_bounds__(256) void pool_copy_kernel(const float* __restrict__ x,
                                                        const float* __restrict__ deg,
                                                        float* __restrict__ fused) {
    const int tid  = threadIdx.x;
    const int lane = tid & 63;
    const int gw   = blockIdx.x * 4 + (tid >> 6);   // wave id 0..8191

    for (int r2 = gw * 2; r2 < NROWS; r2 += 2 * 4 * POOL_BLOCKS) {   // stride 16384
        const float4* x0 = reinterpret_cast<const float4*>(x + (size_t)r2 * HW_TOT);
        float4 v0[4], v1[4];
#pragma unroll
        for (int k = 0; k < 4; ++k) v0[k] = x0[k * 64 + lane];
#pragma unroll
        for (int k = 0; k < 4; ++k) v1[k] = x0[256 + k * 64 + lane];
        float s0 = 0.0f, s1 = 0.0f;
#pragma unroll
        for (int k = 0; k < 4; ++k) {
            s0 += v0[k].x + v0[k].y + v0[k].z + v0[k].w;
            s1 += v1[k].x + v1[k].y + v1[k].z + v1[k].w;
        }
#pragma unroll
        for (int off = 32; off > 0; off >>= 1) {
            s0 += __shfl_xor(s0, off, 64);
            s1 += __shfl_xor(s1, off, 64);
        }
        if (lane == 0) {
            const int b = r2 >> 10;
            const int c = r2 & 1023;
            float2 st;
            st.x = s0 * (1.0f / 1024.0f);
            st.y = s1 * (1.0f / 1024.0f);
            *reinterpret_cast<float2*>(&fused[(size_t)b * FDIM + c]) = st;
        }
    }

    // degraded copy: 49152 float4, first 192 blocks do one pass
    for (int id = blockIdx.x * 256 + tid; id < BATCH * (D_TEXT / 4); id += POOL_BLOCKS * 256) {
        const int b  = id / (D_TEXT / 4);
        const int j4 = id % (D_TEXT / 4);
        reinterpret_cast<float4*>(fused)[(size_t)b * (FDIM / 4) + (D_X / 4) + j4] =
            reinterpret_cast<const float4*>(deg)[id];
    }
}

// ---------------------------------------------------------------------------
// Kernel 2: K-split fp32 GEMM partials: pact[z][m][n] = fused[m, kz:kz+896] @ W[kz:kz+896, n]
// 32m x 64n tile, 128 threads, per-thread 4x4 (float4 LDS reads both sides),
// register-staged double-buffered LDS, grid (8, 28, 2).
// ---------------------------------------------------------------------------
#define BM 32
#define BN 64
#define BK 32
#define KSPLIT 2
#define KPB (FDIM / KSPLIT)     // 896
#define NIT (KPB / BK)          // 28

#define LOADA(k0)                                                                         \
    pa[0] = *reinterpret_cast<const float4*>(A + (size_t)(m0 + ar) * FDIM + (k0) + ak4);  \
    pa[1] = *reinterpret_cast<const float4*>(A + (size_t)(m0 + ar + 16) * FDIM + (k0) + ak4);

#define LOADW(k0)                                                                              \
    pw[0] = *reinterpret_cast<const float4*>(W + (size_t)((k0) + wr) * FDIM + n0 + wc4);       \
    pw[1] = *reinterpret_cast<const float4*>(W + (size_t)((k0) + wr + 8) * FDIM + n0 + wc4);   \
    pw[2] = *reinterpret_cast<const float4*>(W + (size_t)((k0) + wr + 16) * FDIM + n0 + wc4);  \
    pw[3] = *reinterpret_cast<const float4*>(W + (size_t)((k0) + wr + 24) * FDIM + n0 + wc4);

#define STOREA(b)                                                                 \
    As[b][ak4 + 0][ar] = pa[0].x; As[b][ak4 + 1][ar] = pa[0].y;                   \
    As[b][ak4 + 2][ar] = pa[0].z; As[b][ak4 + 3][ar] = pa[0].w;                   \
    As[b][ak4 + 0][ar + 16] = pa[1].x; As[b][ak4 + 1][ar + 16] = pa[1].y;         \
    As[b][ak4 + 2][ar + 16] = pa[1].z; As[b][ak4 + 3][ar + 16] = pa[1].w;

#define STOREW(b)                                                                 \
    *reinterpret_cast<float4*>(&Ws[b][wr][wc4])      = pw[0];                     \
    *reinterpret_cast<float4*>(&Ws[b][wr + 8][wc4])  = pw[1];                     \
    *reinterpret_cast<float4*>(&Ws[b][wr + 16][wc4]) = pw[2];                     \
    *reinterpret_cast<float4*>(&Ws[b][wr + 24][wc4]) = pw[3];

__global__ __launch_bounds__(128) void gemm_split_kernel(const float* __restrict__ A,
                                                         const float* __restrict__ W,
                                                         float* __restrict__ pact) {
    __shared__ float As[2][BK][BM + 4];   // stride 36: float4-aligned, conflict-light
    __shared__ float Ws[2][BK][BN];

    const int tid = threadIdx.x;
    const int tx  = tid & 15;             // 16 n-groups of 4
    const int ty  = tid >> 4;             // 8 m-groups of 4
    const int m0  = blockIdx.x * BM;
    const int n0  = blockIdx.y * BN;
    const int kz  = blockIdx.z * KPB;

    // staging maps (128 threads)
    const int ar  = tid >> 3;             // A rows ar, ar+16
    const int ak4 = (tid & 7) * 4;        // A k-cols
    const int wr  = tid >> 4;             // W k-rows wr, +8, +16, +24
    const int wc4 = (tid & 15) * 4;       // W n-cols

    float4 pa[2], pw[4];

    LOADA(kz); LOADW(kz);
    STOREA(0); STOREW(0);
    LOADA(kz + BK); LOADW(kz + BK);
    __syncthreads();

    float acc[4][4] = {};
    int cur = 0;

    for (int t = 0; t < NIT; ++t) {
#pragma unroll
        for (int kk = 0; kk < BK; ++kk) {
            const float4 a = *reinterpret_cast<const float4*>(&As[cur][kk][ty * 4]);
            const float4 w = *reinterpret_cast<const float4*>(&Ws[cur][kk][tx * 4]);
            const float av[4] = {a.x, a.y, a.z, a.w};
            const float wv[4] = {w.x, w.y, w.z, w.w};
#pragma unroll
            for (int i = 0; i < 4; ++i)
#pragma unroll
                for (int j = 0; j < 4; ++j)
                    acc[i][j] = fmaf(av[i], wv[j], acc[i][j]);
        }
        if (t < NIT - 1) {
            const int nxt = cur ^ 1;
            STOREA(nxt); STOREW(nxt);
            if (t < NIT - 2) {
                const int k0 = kz + (t + 2) * BK;
                LOADA(k0); LOADW(k0);
            }
            __syncthreads();
            cur = nxt;
        }
    }

    float* o = pact + ((size_t)blockIdx.z * BATCH + m0 + ty * 4) * FDIM + n0 + tx * 4;
#pragma unroll
    for (int i = 0; i < 4; ++i) {
        float4 v;
        v.x = acc[i][0]; v.y = acc[i][1]; v.z = acc[i][2]; v.w = acc[i][3];
        *reinterpret_cast<float4*>(o + (size_t)i * FDIM) = v;
    }
}

// ---------------------------------------------------------------------------
// Kernel 3: act = gelu(pact[0]+pact[1]+bias) tile -> LDS, then gate partials
//           part[nb][m][e] = sum_{n in block} act[m][n] * wg[n][e]
// ---------------------------------------------------------------------------
__global__ __launch_bounds__(256) void reduce_gate_kernel(const float* __restrict__ pact,
                                                          const float* __restrict__ bias,
                                                          const float* __restrict__ wg,
                                                          float* __restrict__ part) {
    __shared__ float actS[BM][BN + 1];
    __shared__ float wgs[BN][M_EXP];

    const int tid = threadIdx.x;
    const int m0 = blockIdx.x * BM;
    const int n0 = blockIdx.y * BN;

    // wg slab: 64 rows x 16 = 256 float4
    {
        const int r  = tid >> 2;
        const int c4 = (tid & 3) * 4;
        *reinterpret_cast<float4*>(&wgs[r][c4]) =
            *reinterpret_cast<const float4*>(wg + (size_t)(n0 + r) * M_EXP + c4);
    }

    const int row = tid >> 3;            // 0..31
    const int c8  = (tid & 7) * 8;       // 0..56
    const size_t base = (size_t)(m0 + row) * FDIM + n0 + c8;
#pragma unroll
    for (int h = 0; h < 2; ++h) {
        const float4 p0 = *reinterpret_cast<const float4*>(pact + base + h * 4);
        const float4 p1 = *reinterpret_cast<const float4*>(pact + (size_t)BATCH * FDIM + base + h * 4);
        const float4 bb = *reinterpret_cast<const float4*>(bias + n0 + c8 + h * 4);
        const float vv[4] = {p0.x + p1.x + bb.x, p0.y + p1.y + bb.y,
                             p0.z + p1.z + bb.z, p0.w + p1.w + bb.w};
#pragma unroll
        for (int j = 0; j < 4; ++j)
            actS[row][c8 + h * 4 + j] =
                vv[j] * 0.5f * (1.0f + erff(vv[j] * 0.70710678118654752440f));
    }
    __syncthreads();

    const int pm = tid >> 3;             // 0..31
    const int pe = (tid & 7) * 2;        // 0,2,..,14
    float s0 = 0.0f, s1 = 0.0f;
#pragma unroll
    for (int n = 0; n < BN; ++n) {
        const float a = actS[pm][n];
        s0 = fmaf(a, wgs[n][pe], s0);
        s1 = fmaf(a, wgs[n][pe + 1], s1);
    }
    float* pr = part + ((size_t)blockIdx.y * BATCH + m0 + pm) * M_EXP + pe;
    pr[0] = s0;
    pr[1] = s1;
}

// ---------------------------------------------------------------------------
// Kernel 4: finalize — sum 28 partials (fixed order), softmax, top-2 routing.
// ---------------------------------------------------------------------------
#define NNB (FDIM / BN)   // 28

__global__ __launch_bounds__(64) void finalize_kernel(const float* __restrict__ part,
                                                      float* __restrict__ out) {
    const int b = blockIdx.x * 64 + threadIdx.x;   // 0..255

    float l[M_EXP];
#pragma unroll
    for (int m = 0; m < M_EXP; ++m) l[m] = 0.0f;

    for (int nb = 0; nb < NNB; ++nb) {
        const float4* pr = reinterpret_cast<const float4*>(part + ((size_t)nb * BATCH + b) * M_EXP);
#pragma unroll
        for (int q = 0; q < 4; ++q) {
            const float4 v = pr[q];
            l[q * 4 + 0] += v.x;
            l[q * 4 + 1] += v.y;
            l[q * 4 + 2] += v.z;
            l[q * 4 + 3] += v.w;
        }
    }

    float mx = l[0];
#pragma unroll
    for (int m = 1; m < M_EXP; ++m) mx = fmaxf(mx, l[m]);
    float e[M_EXP], s = 0.0f;
#pragma unroll
    for (int m = 0; m < M_EXP; ++m) { e[m] = expf(l[m] - mx); s += e[m]; }
    const float inv = 1.0f / s;
#pragma unroll
    for (int m = 0; m < M_EXP; ++m) out[OUT_PROBS + b * M_EXP + m] = e[m] * inv;

    int i0 = 0; float v0 = l[0];
#pragma unroll
    for (int m = 1; m < M_EXP; ++m) if (l[m] > v0) { v0 = l[m]; i0 = m; }
    int i1 = -1; float v1 = -INFINITY;
#pragma unroll
    for (int m = 0; m < M_EXP; ++m) if (m != i0 && l[m] > v1) { v1 = l[m]; i1 = m; }

    const float t = expf(v1 - v0);
    const float g0 = 1.0f / (1.0f + t);
    const float g1 = t * g0;

#pragma unroll
    for (int m = 0; m < M_EXP; ++m) out[OUT_GATES + b * M_EXP + m] = 0.0f;
    out[OUT_GATES + b * M_EXP + i0] = g0;
    out[OUT_GATES + b * M_EXP + i1] = g1;

    out[OUT_IDX + b * 2 + 0] = (float)i0;
    out[OUT_IDX + b * 2 + 1] = (float)i1;

    if (b == 0) out[OUT_LOSS] = 0.0f;
}

// ---------------------------------------------------------------------------
extern "C" void kernel_launch(void* const* d_in, const int* in_sizes, int n_in,
                              void* d_out, int out_size, void* d_ws, size_t ws_size,
                              hipStream_t stream) {
    const float* x        = (const float*)d_in[0];
    const float* degraded = (const float*)d_in[1];
    const float* w_fusion = (const float*)d_in[2];
    const float* b_fusion = (const float*)d_in[3];
    const float* w_gate   = (const float*)d_in[4];
    float* out = (float*)d_out;

    float* fused = (float*)d_ws;                              // 256*1792 f32      (1.84 MB)
    float* pact  = fused + (size_t)BATCH * FDIM;              // 2*256*1792 f32    (3.67 MB)
    float* part  = pact + (size_t)KSPLIT * BATCH * FDIM;      // 28*256*16 f32     (0.46 MB)

    // 1) pool + degraded copy (persistent grid-stride)
    pool_copy_kernel<<<POOL_BLOCKS, 256, 0, stream>>>(x, degraded, fused);

    // 2) K-split fusion GEMM partials: grid (8, 28, 2), 128 threads
    gemm_split_kernel<<<dim3(BATCH / BM, FDIM / BN, KSPLIT), 128, 0, stream>>>(fused, w_fusion, pact);

    // 3) reduce + bias + gelu + gate partials: grid (8, 28)
    reduce_gate_kernel<<<dim3(BATCH / BM, FDIM / BN), 256, 0, stream>>>(pact, b_fusion, w_gate, part);

    // 4) finalize
    finalize_kernel<<<BATCH / 64, 64, 0, stream>>>(part, out);
}